// Round 1
// baseline (715.395 us; speedup 1.0000x reference)
//
#include <hip/hip_runtime.h>

// GCNe: 3-layer edge-weighted GCN + mean pool + linear head.
// N=100000 nodes, E=1000000 edges, F=H=64, G=256 graphs, C=10 classes.
//
// Strategy: counting-sort edges by dst into CSR once per launch (deterministic
// work), then each conv layer is atomic-free: one wave per node, lane=feature.

#define GCN_F 64
#define GCN_C 10

// ---------------------------------------------------------------- histogram
__global__ void hist_kernel(const int* __restrict__ dst, int* __restrict__ cnt, int E) {
    int e = blockIdx.x * blockDim.x + threadIdx.x;
    if (e < E) atomicAdd(&cnt[dst[e]], 1);
}

// ------------------------------------------------- single-block chunked scan
#define SCAN_ITEMS 8
__global__ void scan_kernel(const int* __restrict__ cnt, int* __restrict__ offsets, int n) {
    __shared__ int buf[1024];
    __shared__ int s_carry;
    int tid = threadIdx.x;
    if (tid == 0) s_carry = 0;
    __syncthreads();
    const int CHUNK = 1024 * SCAN_ITEMS;
    for (int base = 0; base < n; base += CHUNK) {
        int vals[SCAN_ITEMS];
        int idx0 = base + tid * SCAN_ITEMS;
        int local = 0;
#pragma unroll
        for (int k = 0; k < SCAN_ITEMS; ++k) {
            int i = idx0 + k;
            vals[k] = (i < n) ? cnt[i] : 0;
            local += vals[k];
        }
        buf[tid] = local;
        __syncthreads();
        // Hillis-Steele inclusive scan over 1024 thread-partials
        for (int off = 1; off < 1024; off <<= 1) {
            int t = (tid >= off) ? buf[tid - off] : 0;
            __syncthreads();
            buf[tid] += t;
            __syncthreads();
        }
        int excl_thread = buf[tid] - local;
        int chunk_total = buf[1023];
        int carry = s_carry;
        int run = carry + excl_thread;
#pragma unroll
        for (int k = 0; k < SCAN_ITEMS; ++k) {
            int i = idx0 + k;
            if (i < n) offsets[i] = run;
            run += vals[k];
        }
        __syncthreads();                 // all reads of s_carry/buf done
        if (tid == 0) s_carry = carry + chunk_total;
        __syncthreads();
    }
    if (tid == 0) offsets[n] = s_carry;
}

// --------------------------------------------------------- scatter into CSR
__global__ void scatter_kernel(const int* __restrict__ src, const int* __restrict__ dst,
                               const float* __restrict__ ew, const int* __restrict__ offsets,
                               int* __restrict__ cursor, int2* __restrict__ sorted, int E) {
    int e = blockIdx.x * blockDim.x + threadIdx.x;
    if (e < E) {
        int d = dst[e];
        int pos = offsets[d] + atomicAdd(&cursor[d], 1);
        int2 rec;
        rec.x = src[e];
        rec.y = __float_as_int(ew[e]);
        sorted[pos] = rec;
    }
}

// ---------------------------------------- fused aggregate + 2xGEMV + bias + relu
// One wave per node. lane = feature index. Weight columns live in VGPRs.
__global__ __launch_bounds__(256) void layer_kernel(
    const float* __restrict__ xin, const int* __restrict__ offsets,
    const int2* __restrict__ edges, const float* __restrict__ Wr,
    const float* __restrict__ Ws, const float* __restrict__ b,
    float* __restrict__ out, int n)
{
    __shared__ float rowAgg[4][GCN_F];
    __shared__ float rowX[4][GCN_F];
    int tid  = threadIdx.x;
    int lane = tid & 63;
    int wave = tid >> 6;

    // per-lane weight columns (L2-resident; coalesced 256B per instr)
    float wr[GCN_F], ws[GCN_F];
#pragma unroll
    for (int f = 0; f < GCN_F; ++f) {
        wr[f] = Wr[f * GCN_F + lane];
        ws[f] = Ws[f * GCN_F + lane];
    }
    float bias = b[lane];

    int gwave  = blockIdx.x * 4 + wave;
    int nwaves = gridDim.x * 4;
    for (int node = gwave; node < n; node += nwaves) {
        float xv = xin[node * GCN_F + lane];
        int p0 = offsets[node], p1 = offsets[node + 1];
        float acc = 0.f;
        int p = p0;
        for (; p + 4 <= p1; p += 4) {               // 4 independent gather chains
            int2 r0 = edges[p + 0];
            int2 r1 = edges[p + 1];
            int2 r2 = edges[p + 2];
            int2 r3 = edges[p + 3];
            float a0 = xin[r0.x * GCN_F + lane];
            float a1 = xin[r1.x * GCN_F + lane];
            float a2 = xin[r2.x * GCN_F + lane];
            float a3 = xin[r3.x * GCN_F + lane];
            acc += a0 * __int_as_float(r0.y);
            acc += a1 * __int_as_float(r1.y);
            acc += a2 * __int_as_float(r2.y);
            acc += a3 * __int_as_float(r3.y);
        }
        for (; p < p1; ++p) {
            int2 r = edges[p];
            acc += xin[r.x * GCN_F + lane] * __int_as_float(r.y);
        }

        // stage rows in LDS (wave-internal; no block barrier needed)
        rowAgg[wave][lane] = acc;
        rowX[wave][lane]   = xv;

        float o = bias;
#pragma unroll
        for (int f4 = 0; f4 < GCN_F / 4; ++f4) {
            float4 a4 = *reinterpret_cast<const float4*>(&rowAgg[wave][f4 * 4]);
            float4 x4 = *reinterpret_cast<const float4*>(&rowX[wave][f4 * 4]);
            o += a4.x * wr[f4 * 4 + 0] + a4.y * wr[f4 * 4 + 1] +
                 a4.z * wr[f4 * 4 + 2] + a4.w * wr[f4 * 4 + 3];
            o += x4.x * ws[f4 * 4 + 0] + x4.y * ws[f4 * 4 + 1] +
                 x4.z * ws[f4 * 4 + 2] + x4.w * ws[f4 * 4 + 3];
        }
        out[node * GCN_F + lane] = fmaxf(o, 0.f);
    }
}

// ------------------------------------------------- mean pool + linear head
__global__ __launch_bounds__(256) void pool_kernel(
    const float* __restrict__ h, const int* __restrict__ batch,
    const float* __restrict__ Wl, const float* __restrict__ bl,
    float* __restrict__ out, int n)
{
    int g    = blockIdx.x;
    int tid  = threadIdx.x;
    int lane = tid & 63;
    int wave = tid >> 6;

    // lower_bound(batch, g) / lower_bound(batch, g+1) — batch is sorted
    int i0, i1;
    {
        int lo = 0, hi = n;
        while (lo < hi) { int mid = (lo + hi) >> 1; if (batch[mid] < g) lo = mid + 1; else hi = mid; }
        i0 = lo;
        lo = i0; hi = n;
        while (lo < hi) { int mid = (lo + hi) >> 1; if (batch[mid] < g + 1) lo = mid + 1; else hi = mid; }
        i1 = lo;
    }

    float s = 0.f;
    for (int i = i0 + wave; i < i1; i += 4) s += h[i * GCN_F + lane];

    __shared__ float sp[4][GCN_F];
    sp[wave][lane] = s;
    __syncthreads();
    if (wave == 0) {
        float tot = sp[0][lane] + sp[1][lane] + sp[2][lane] + sp[3][lane];
        float cntf = (float)(i1 - i0);
        sp[0][lane] = tot / fmaxf(cntf, 1.f);
    }
    __syncthreads();
    if (tid < GCN_C) {
        float o = bl[tid];
#pragma unroll
        for (int j = 0; j < GCN_F; ++j) o += sp[0][j] * Wl[j * GCN_C + tid];
        out[g * GCN_C + tid] = o;
    }
}

// --------------------------------------------------------------------------
extern "C" void kernel_launch(void* const* d_in, const int* in_sizes, int n_in,
                              void* d_out, int out_size, void* d_ws, size_t ws_size,
                              hipStream_t stream) {
    const float* x     = (const float*)d_in[0];
    const int*   ei    = (const int*)d_in[1];
    const float* ew    = (const float*)d_in[2];
    const int*   batch = (const int*)d_in[3];
    const float* W1r   = (const float*)d_in[4];
    const float* W1s   = (const float*)d_in[5];
    const float* b1    = (const float*)d_in[6];
    const float* W2r   = (const float*)d_in[7];
    const float* W2s   = (const float*)d_in[8];
    const float* b2    = (const float*)d_in[9];
    const float* W3r   = (const float*)d_in[10];
    const float* W3s   = (const float*)d_in[11];
    const float* b3    = (const float*)d_in[12];
    const float* Wl    = (const float*)d_in[13];
    const float* bl    = (const float*)d_in[14];
    float* out = (float*)d_out;

    const int N = in_sizes[0] / GCN_F;   // 100000
    const int E = in_sizes[2];           // 1000000
    const int G = out_size / GCN_C;      // 256

    const int* src = ei;
    const int* dst = ei + E;

    // workspace layout (16B aligned)
    char* ws = (char*)d_ws;
    size_t off = 0;
    int* cnt = (int*)(ws + off);            off += (size_t)N * 4;          // 400000
    int* offsets = (int*)(ws + off);        off += ((size_t)(N + 1) * 4 + 15) & ~(size_t)15;
    int2* sorted = (int2*)(ws + off);       off += (size_t)E * 8;          // 8 MB
    float* h1 = (float*)(ws + off);         off += (size_t)N * GCN_F * 4;  // 25.6 MB
    float* h2 = (float*)(ws + off);         off += (size_t)N * GCN_F * 4;  // 25.6 MB

    int eblocks = (E + 255) / 256;

    hipMemsetAsync(cnt, 0, (size_t)N * 4, stream);
    hist_kernel<<<eblocks, 256, 0, stream>>>(dst, cnt, E);
    scan_kernel<<<1, 1024, 0, stream>>>(cnt, offsets, N);
    hipMemsetAsync(cnt, 0, (size_t)N * 4, stream);  // reuse as cursor
    scatter_kernel<<<eblocks, 256, 0, stream>>>(src, dst, ew, offsets, cnt, sorted, E);

    const int LBLK = 1024;
    layer_kernel<<<LBLK, 256, 0, stream>>>(x,  offsets, sorted, W1r, W1s, b1, h1, N);
    layer_kernel<<<LBLK, 256, 0, stream>>>(h1, offsets, sorted, W2r, W2s, b2, h2, N);
    layer_kernel<<<LBLK, 256, 0, stream>>>(h2, offsets, sorted, W3r, W3s, b3, h1, N);

    pool_kernel<<<G, 256, 0, stream>>>(h1, batch, Wl, bl, out, N);
}

// Round 2
// 513.304 us; speedup vs baseline: 1.3937x; 1.3937x over previous
//
#include <hip/hip_runtime.h>

// GCNe: 3-layer edge-weighted GCN + mean pool + linear head.
// N=100000, E=1000000, F=H=64, G=256, C=10.
//
// CSR by dst built per launch (hist -> 3-kernel scan -> scatter), then each
// layer: one wave per node, lane = feature. Edges wave-loaded 64 at a time and
// broadcast via v_readlane (all gathers independent, SGPR-base addressing).
// GEMV with register-resident weight columns + readlane broadcast of acc/x.

#define GCN_F 64
#define GCN_C 10
#define SCAN_CHUNK 2048   // 256 threads * 8 items

__device__ __forceinline__ float readlane_f(float v, int l) {
    return __int_as_float(__builtin_amdgcn_readlane(__float_as_int(v), l));
}

// ---------------------------------------------------------------- histogram
__global__ __launch_bounds__(256) void hist_kernel(const int* __restrict__ dst,
                                                   int* __restrict__ cnt, int E) {
    int e = blockIdx.x * blockDim.x + threadIdx.x;
    if (e < E) atomicAdd(&cnt[dst[e]], 1);
}

// ------------------------------------------------------ scan pass 1: partials
__global__ __launch_bounds__(256) void scan_part1(const int* __restrict__ cnt,
                                                  int* __restrict__ part, int n) {
    int b = blockIdx.x, tid = threadIdx.x, lane = tid & 63, wave = tid >> 6;
    int i0 = b * SCAN_CHUNK + tid * 8;
    int s = 0;
#pragma unroll
    for (int k = 0; k < 8; ++k) { int i = i0 + k; if (i < n) s += cnt[i]; }
#pragma unroll
    for (int off = 1; off < 64; off <<= 1) s += __shfl_xor(s, off);
    __shared__ int wsum[4];
    if (lane == 0) wsum[wave] = s;
    __syncthreads();
    if (tid == 0) part[b] = wsum[0] + wsum[1] + wsum[2] + wsum[3];
}

// --------------------------------------- scan pass 2: scan partials (1 wave)
__global__ void scan_part2(int* __restrict__ part, int* __restrict__ offsets,
                           int nb, int n) {
    int lane = threadIdx.x;
    int carry = 0;
    for (int base = 0; base < nb; base += 64) {
        int i = base + lane;
        int v = (i < nb) ? part[i] : 0;
        int sc = v;
#pragma unroll
        for (int off = 1; off < 64; off <<= 1) {
            int t = __shfl_up(sc, off);
            if (lane >= off) sc += t;
        }
        if (i < nb) part[i] = carry + sc - v;   // exclusive
        carry += __shfl(sc, 63);
    }
    if (lane == 0) offsets[n] = carry;          // total = E
}

// ------------------------------------------------------- scan pass 3: final
__global__ __launch_bounds__(256) void scan_final(const int* __restrict__ cnt,
                                                  const int* __restrict__ part,
                                                  int* __restrict__ offsets, int n) {
    int b = blockIdx.x, tid = threadIdx.x, lane = tid & 63, wave = tid >> 6;
    int i0 = b * SCAN_CHUNK + tid * 8;
    int v[8];
    int s = 0;
#pragma unroll
    for (int k = 0; k < 8; ++k) {
        int i = i0 + k;
        v[k] = (i < n) ? cnt[i] : 0;
        s += v[k];
    }
    int sc = s;
#pragma unroll
    for (int off = 1; off < 64; off <<= 1) {
        int t = __shfl_up(sc, off);
        if (lane >= off) sc += t;
    }
    __shared__ int wsum[4];
    if (lane == 63) wsum[wave] = sc;
    __syncthreads();
    int wbase = 0;
    for (int w = 0; w < wave; ++w) wbase += wsum[w];
    int run = part[b] + wbase + (sc - s);       // exclusive prefix for this thread
#pragma unroll
    for (int k = 0; k < 8; ++k) {
        int i = i0 + k;
        if (i < n) offsets[i] = run;
        run += v[k];
    }
}

// --------------------------------------------------------- scatter into CSR
__global__ __launch_bounds__(256) void scatter_kernel(
    const int* __restrict__ src, const int* __restrict__ dst,
    const float* __restrict__ ew, const int* __restrict__ offsets,
    int* __restrict__ cursor, int2* __restrict__ sorted, int E) {
    int e = blockIdx.x * blockDim.x + threadIdx.x;
    if (e < E) {
        int d = dst[e];
        int pos = offsets[d] + atomicAdd(&cursor[d], 1);
        int2 rec;
        rec.x = src[e];
        rec.y = __float_as_int(ew[e]);
        sorted[pos] = rec;
    }
}

// ---------------------------------- fused aggregate + 2xGEMV + bias + relu
// One wave per node. lane = feature. Weight columns register-resident
// (launch_bounds(256,3): VGPR budget 170 > 128 weights + working set).
__global__ __launch_bounds__(256, 3) void layer_kernel(
    const float* __restrict__ xin, const int* __restrict__ offsets,
    const int2* __restrict__ edges, const float* __restrict__ Wr,
    const float* __restrict__ Ws, const float* __restrict__ b,
    float* __restrict__ out, int n)
{
    int tid  = threadIdx.x;
    int lane = tid & 63;
    int wave = tid >> 6;

    float wr[GCN_F], ws[GCN_F];
#pragma unroll
    for (int f = 0; f < GCN_F; ++f) {
        wr[f] = Wr[f * GCN_F + lane];
        ws[f] = Ws[f * GCN_F + lane];
    }
    float bias = b[lane];

    int gwave  = blockIdx.x * 4 + wave;
    int nwaves = gridDim.x * 4;
    for (int node = gwave; node < n; node += nwaves) {
        int p0 = offsets[node], p1 = offsets[node + 1];
        float xv = xin[(size_t)node * GCN_F + lane];
        float acc = 0.f;

        for (int base = p0; base < p1; base += 64) {
            int m = min(64, p1 - base);
            int2 er = make_int2(0, 0);
            if (lane < m) er = edges[base + lane];   // wave-load edge chunk
            int j = 0;
            for (; j + 4 <= m; j += 4) {             // broadcast + independent gathers
                int   s0 = __builtin_amdgcn_readlane(er.x, j + 0);
                int   s1 = __builtin_amdgcn_readlane(er.x, j + 1);
                int   s2 = __builtin_amdgcn_readlane(er.x, j + 2);
                int   s3 = __builtin_amdgcn_readlane(er.x, j + 3);
                float w0 = __int_as_float(__builtin_amdgcn_readlane(er.y, j + 0));
                float w1 = __int_as_float(__builtin_amdgcn_readlane(er.y, j + 1));
                float w2 = __int_as_float(__builtin_amdgcn_readlane(er.y, j + 2));
                float w3 = __int_as_float(__builtin_amdgcn_readlane(er.y, j + 3));
                float a0 = xin[(size_t)s0 * GCN_F + lane];
                float a1 = xin[(size_t)s1 * GCN_F + lane];
                float a2 = xin[(size_t)s2 * GCN_F + lane];
                float a3 = xin[(size_t)s3 * GCN_F + lane];
                acc = fmaf(a0, w0, acc);
                acc = fmaf(a1, w1, acc);
                acc = fmaf(a2, w2, acc);
                acc = fmaf(a3, w3, acc);
            }
            for (; j < m; ++j) {
                int   sj = __builtin_amdgcn_readlane(er.x, j);
                float wj = __int_as_float(__builtin_amdgcn_readlane(er.y, j));
                acc = fmaf(xin[(size_t)sj * GCN_F + lane], wj, acc);
            }
        }

        // GEMV: o[lane] = bias + sum_f agg[f]*Wr[f][lane] + x[f]*Ws[f][lane]
        float o = bias;
#pragma unroll
        for (int f = 0; f < GCN_F; ++f) {
            o = fmaf(readlane_f(acc, f), wr[f], o);
            o = fmaf(readlane_f(xv,  f), ws[f], o);
        }
        out[(size_t)node * GCN_F + lane] = fmaxf(o, 0.f);
    }
}

// ------------------------------------------------- mean pool + linear head
__global__ __launch_bounds__(256) void pool_kernel(
    const float* __restrict__ h, const int* __restrict__ batch,
    const float* __restrict__ Wl, const float* __restrict__ bl,
    float* __restrict__ out, int n)
{
    int g    = blockIdx.x;
    int tid  = threadIdx.x;
    int lane = tid & 63;
    int wave = tid >> 6;

    int i0, i1;
    {
        int lo = 0, hi = n;
        while (lo < hi) { int mid = (lo + hi) >> 1; if (batch[mid] < g) lo = mid + 1; else hi = mid; }
        i0 = lo;
        lo = i0; hi = n;
        while (lo < hi) { int mid = (lo + hi) >> 1; if (batch[mid] < g + 1) lo = mid + 1; else hi = mid; }
        i1 = lo;
    }

    float s = 0.f;
    for (int i = i0 + wave; i < i1; i += 4) s += h[(size_t)i * GCN_F + lane];

    __shared__ float sp[4][GCN_F];
    sp[wave][lane] = s;
    __syncthreads();
    if (wave == 0) {
        float tot = sp[0][lane] + sp[1][lane] + sp[2][lane] + sp[3][lane];
        float cntf = (float)(i1 - i0);
        sp[0][lane] = tot / fmaxf(cntf, 1.f);
    }
    __syncthreads();
    if (tid < GCN_C) {
        float o = bl[tid];
#pragma unroll
        for (int j = 0; j < GCN_F; ++j) o += sp[0][j] * Wl[j * GCN_C + tid];
        out[g * GCN_C + tid] = o;
    }
}

// --------------------------------------------------------------------------
extern "C" void kernel_launch(void* const* d_in, const int* in_sizes, int n_in,
                              void* d_out, int out_size, void* d_ws, size_t ws_size,
                              hipStream_t stream) {
    const float* x     = (const float*)d_in[0];
    const int*   ei    = (const int*)d_in[1];
    const float* ew    = (const float*)d_in[2];
    const int*   batch = (const int*)d_in[3];
    const float* W1r   = (const float*)d_in[4];
    const float* W1s   = (const float*)d_in[5];
    const float* b1    = (const float*)d_in[6];
    const float* W2r   = (const float*)d_in[7];
    const float* W2s   = (const float*)d_in[8];
    const float* b2    = (const float*)d_in[9];
    const float* W3r   = (const float*)d_in[10];
    const float* W3s   = (const float*)d_in[11];
    const float* b3    = (const float*)d_in[12];
    const float* Wl    = (const float*)d_in[13];
    const float* bl    = (const float*)d_in[14];
    float* out = (float*)d_out;

    const int N = in_sizes[0] / GCN_F;   // 100000
    const int E = in_sizes[2];           // 1000000
    const int G = out_size / GCN_C;      // 256

    const int* src = ei;
    const int* dst = ei + E;

    // workspace layout (16B aligned)
    char* ws = (char*)d_ws;
    size_t off = 0;
    int* cnt     = (int*)(ws + off);  off += (size_t)N * 4;
    int* offsets = (int*)(ws + off);  off += ((size_t)(N + 1) * 4 + 15) & ~(size_t)15;
    int* part    = (int*)(ws + off);  off += 4096;                      // scan partials
    int2* sorted = (int2*)(ws + off); off += (size_t)E * 8;
    float* h1    = (float*)(ws + off); off += (size_t)N * GCN_F * 4;
    float* h2    = (float*)(ws + off); off += (size_t)N * GCN_F * 4;

    int eblocks = (E + 255) / 256;
    int nscan   = (N + SCAN_CHUNK - 1) / SCAN_CHUNK;

    hipMemsetAsync(cnt, 0, (size_t)N * 4, stream);
    hist_kernel<<<eblocks, 256, 0, stream>>>(dst, cnt, E);
    scan_part1<<<nscan, 256, 0, stream>>>(cnt, part, N);
    scan_part2<<<1, 64, 0, stream>>>(part, offsets, nscan, N);
    scan_final<<<nscan, 256, 0, stream>>>(cnt, part, offsets, N);
    hipMemsetAsync(cnt, 0, (size_t)N * 4, stream);  // reuse as cursor
    scatter_kernel<<<eblocks, 256, 0, stream>>>(src, dst, ew, offsets, cnt, sorted, E);

    const int LBLK = 2048;
    layer_kernel<<<LBLK, 256, 0, stream>>>(x,  offsets, sorted, W1r, W1s, b1, h1, N);
    layer_kernel<<<LBLK, 256, 0, stream>>>(h1, offsets, sorted, W2r, W2s, b2, h2, N);
    layer_kernel<<<LBLK, 256, 0, stream>>>(h2, offsets, sorted, W3r, W3s, b3, h1, N);

    pool_kernel<<<G, 256, 0, stream>>>(h1, batch, Wl, bl, out, N);
}

// Round 3
// 334.777 us; speedup vs baseline: 2.1369x; 1.5333x over previous
//
#include <hip/hip_runtime.h>

// GCNe: 3-layer edge-weighted GCN + mean pool + linear head.
// N=100000, E=1000000, F=H=64, G=256, C=10.
//
// R3: split each layer into SpMM (bf16 gather/accumulate, one wave per node)
// and an MFMA bf16 GEMM (relu(agg@Wr + x@Ws + b)). CSR built per launch.

#define GCN_F 64
#define GCN_C 10
#define SCAN_CHUNK 2048   // 256 threads * 8 items

typedef __attribute__((ext_vector_type(8))) short bf16x8;
typedef __attribute__((ext_vector_type(4))) float f32x4;

__device__ __forceinline__ unsigned short f2b(float v) {
    union { float f; unsigned int u; } c; c.f = v;
    unsigned int u = c.u;
    return (unsigned short)((u + 0x7FFFu + ((u >> 16) & 1u)) >> 16);  // RNE
}
__device__ __forceinline__ float b2f(unsigned short u) {
    union { unsigned int u; float f; } c; c.u = ((unsigned int)u) << 16; return c.f;
}

// ---------------------------------------------------------------- histogram
__global__ __launch_bounds__(256) void hist_kernel(const int* __restrict__ dst,
                                                   int* __restrict__ cnt, int E) {
    int e = blockIdx.x * blockDim.x + threadIdx.x;
    if (e < E) atomicAdd(&cnt[dst[e]], 1);
}

// ------------------------------------------------------ scan pass 1: partials
__global__ __launch_bounds__(256) void scan_part1(const int* __restrict__ cnt,
                                                  int* __restrict__ part, int n) {
    int b = blockIdx.x, tid = threadIdx.x, lane = tid & 63, wave = tid >> 6;
    int i0 = b * SCAN_CHUNK + tid * 8;
    int s = 0;
#pragma unroll
    for (int k = 0; k < 8; ++k) { int i = i0 + k; if (i < n) s += cnt[i]; }
#pragma unroll
    for (int off = 1; off < 64; off <<= 1) s += __shfl_xor(s, off);
    __shared__ int wsum[4];
    if (lane == 0) wsum[wave] = s;
    __syncthreads();
    if (tid == 0) part[b] = wsum[0] + wsum[1] + wsum[2] + wsum[3];
}

// --------------------------------------- scan pass 2: scan partials (1 wave)
__global__ void scan_part2(int* __restrict__ part, int* __restrict__ offsets,
                           int nb, int n) {
    int lane = threadIdx.x;
    int carry = 0;
    for (int base = 0; base < nb; base += 64) {
        int i = base + lane;
        int v = (i < nb) ? part[i] : 0;
        int sc = v;
#pragma unroll
        for (int off = 1; off < 64; off <<= 1) {
            int t = __shfl_up(sc, off);
            if (lane >= off) sc += t;
        }
        if (i < nb) part[i] = carry + sc - v;   // exclusive
        carry += __shfl(sc, 63);
    }
    if (lane == 0) offsets[n] = carry;          // total = E
}

// ------------------------------------------------------- scan pass 3: final
__global__ __launch_bounds__(256) void scan_final(const int* __restrict__ cnt,
                                                  const int* __restrict__ part,
                                                  int* __restrict__ offsets, int n) {
    int b = blockIdx.x, tid = threadIdx.x, lane = tid & 63, wave = tid >> 6;
    int i0 = b * SCAN_CHUNK + tid * 8;
    int v[8];
    int s = 0;
#pragma unroll
    for (int k = 0; k < 8; ++k) {
        int i = i0 + k;
        v[k] = (i < n) ? cnt[i] : 0;
        s += v[k];
    }
    int sc = s;
#pragma unroll
    for (int off = 1; off < 64; off <<= 1) {
        int t = __shfl_up(sc, off);
        if (lane >= off) sc += t;
    }
    __shared__ int wsum[4];
    if (lane == 63) wsum[wave] = sc;
    __syncthreads();
    int wbase = 0;
    for (int w = 0; w < wave; ++w) wbase += wsum[w];
    int run = part[b] + wbase + (sc - s);
#pragma unroll
    for (int k = 0; k < 8; ++k) {
        int i = i0 + k;
        if (i < n) offsets[i] = run;
        run += v[k];
    }
}

// --------------------------------------------------------- scatter into CSR
__global__ __launch_bounds__(256) void scatter_kernel(
    const int* __restrict__ src, const int* __restrict__ dst,
    const float* __restrict__ ew, const int* __restrict__ offsets,
    int* __restrict__ cursor, int2* __restrict__ sorted, int E) {
    int e = blockIdx.x * blockDim.x + threadIdx.x;
    if (e < E) {
        int d = dst[e];
        int pos = offsets[d] + atomicAdd(&cursor[d], 1);
        int2 rec;
        rec.x = src[e];
        rec.y = __float_as_int(ew[e]);
        sorted[pos] = rec;
    }
}

// ----------------------------------------------------- fp32 -> bf16 convert
__global__ __launch_bounds__(256) void cvt_kernel(const float* __restrict__ in,
                                                  unsigned short* __restrict__ out,
                                                  int n4) {
    int stride = gridDim.x * blockDim.x;
    for (int i = blockIdx.x * blockDim.x + threadIdx.x; i < n4; i += stride) {
        float4 v = reinterpret_cast<const float4*>(in)[i];
        ushort4 o;
        o.x = f2b(v.x); o.y = f2b(v.y); o.z = f2b(v.z); o.w = f2b(v.w);
        reinterpret_cast<ushort4*>(out)[i] = o;
    }
}

// -------------------------------------------- SpMM: agg[dst] += ew * x[src]
// One wave per node, lane = feature. bf16 rows (128B gathers), fp32 accum.
__global__ __launch_bounds__(256) void spmm_kernel(
    const unsigned short* __restrict__ xin, const int* __restrict__ offsets,
    const int2* __restrict__ edges, unsigned short* __restrict__ out, int n)
{
    int tid = threadIdx.x, lane = tid & 63, wave = tid >> 6;
    int gw = blockIdx.x * 4 + wave, nw = gridDim.x * 4;
    for (int node = gw; node < n; node += nw) {
        int p0 = offsets[node], p1 = offsets[node + 1];
        float acc = 0.f;
        for (int base = p0; base < p1; base += 64) {
            int m = min(64, p1 - base);
            int2 er = make_int2(0, 0);
            if (lane < m) er = edges[base + lane];
            int j = 0;
            for (; j + 8 <= m; j += 8) {
                float a[8], w[8];
#pragma unroll
                for (int q = 0; q < 8; ++q) {
                    int   s = __builtin_amdgcn_readlane(er.x, j + q);
                    w[q] = __int_as_float(__builtin_amdgcn_readlane(er.y, j + q));
                    a[q] = b2f(xin[(size_t)s * GCN_F + lane]);
                }
#pragma unroll
                for (int q = 0; q < 8; ++q) acc = fmaf(a[q], w[q], acc);
            }
            for (; j < m; ++j) {
                int   s = __builtin_amdgcn_readlane(er.x, j);
                float w = __int_as_float(__builtin_amdgcn_readlane(er.y, j));
                acc = fmaf(b2f(xin[(size_t)s * GCN_F + lane]), w, acc);
            }
        }
        out[(size_t)node * GCN_F + lane] = f2b(acc);
    }
}

// ---------------------- GEMM: h = relu(agg @ Wr + x @ Ws + b), bf16 via MFMA
// 16x16x32 bf16 MFMA. A: lane holds row=l&15, k=(l>>4)*8+j. B: col=l&15, same k.
// C/D: col=lane&15, row=(lane>>4)*4+reg.
__global__ __launch_bounds__(256) void gemm_kernel(
    const unsigned short* __restrict__ agg, const unsigned short* __restrict__ xin,
    const float* __restrict__ Wr, const float* __restrict__ Ws,
    const float* __restrict__ b, unsigned short* __restrict__ out, int n)
{
    // B fragments pre-swizzled: [op][ks][ct][lane][j]
    __shared__ __align__(16) unsigned short bfrag[2][2][4][64][8];   // 16 KB
    int tid = threadIdx.x;
    for (int i = tid; i < 8192; i += 256) {
        int op = i >> 12;
        int ks = (i >> 11) & 1;
        int ct = (i >> 9) & 3;
        int l  = (i >> 3) & 63;
        int j  = i & 7;
        int k   = ks * 32 + (l >> 4) * 8 + j;
        int col = ct * 16 + (l & 15);
        const float* W = op ? Ws : Wr;
        ((unsigned short*)bfrag)[i] = f2b(W[k * GCN_F + col]);
    }
    __syncthreads();

    int lane = tid & 63, wave = tid >> 6;
    int l15 = lane & 15, lhi = lane >> 4;

    bf16x8 B[2][2][4];
#pragma unroll
    for (int op = 0; op < 2; ++op)
#pragma unroll
        for (int ks = 0; ks < 2; ++ks)
#pragma unroll
            for (int ct = 0; ct < 4; ++ct)
                B[op][ks][ct] = *reinterpret_cast<const bf16x8*>(&bfrag[op][ks][ct][lane][0]);

    float bias[4];
#pragma unroll
    for (int ct = 0; ct < 4; ++ct) bias[ct] = b[ct * 16 + l15];

    int ntiles = (n + 15) >> 4;
    for (int t = blockIdx.x * 4 + wave; t < ntiles; t += gridDim.x * 4) {
        int row = t * 16 + l15;
        int arow = min(row, n - 1);
        const unsigned short* ap = agg + (size_t)arow * GCN_F + lhi * 8;
        const unsigned short* xp = xin + (size_t)arow * GCN_F + lhi * 8;
        bf16x8 a0 = *reinterpret_cast<const bf16x8*>(ap);
        bf16x8 a1 = *reinterpret_cast<const bf16x8*>(ap + 32);
        bf16x8 x0 = *reinterpret_cast<const bf16x8*>(xp);
        bf16x8 x1 = *reinterpret_cast<const bf16x8*>(xp + 32);
#pragma unroll
        for (int ct = 0; ct < 4; ++ct) {
            f32x4 acc = {0.f, 0.f, 0.f, 0.f};
            acc = __builtin_amdgcn_mfma_f32_16x16x32_bf16(a0, B[0][0][ct], acc, 0, 0, 0);
            acc = __builtin_amdgcn_mfma_f32_16x16x32_bf16(a1, B[0][1][ct], acc, 0, 0, 0);
            acc = __builtin_amdgcn_mfma_f32_16x16x32_bf16(x0, B[1][0][ct], acc, 0, 0, 0);
            acc = __builtin_amdgcn_mfma_f32_16x16x32_bf16(x1, B[1][1][ct], acc, 0, 0, 0);
            int col = ct * 16 + l15;
#pragma unroll
            for (int r = 0; r < 4; ++r) {
                int orow = t * 16 + lhi * 4 + r;
                if (orow < n) {
                    float v = fmaxf(acc[r] + bias[ct], 0.f);
                    out[(size_t)orow * GCN_F + col] = f2b(v);
                }
            }
        }
    }
}

// ------------------------------------------------- mean pool + linear head
__global__ __launch_bounds__(256) void pool_kernel(
    const unsigned short* __restrict__ h, const int* __restrict__ batch,
    const float* __restrict__ Wl, const float* __restrict__ bl,
    float* __restrict__ out, int n)
{
    int g    = blockIdx.x;
    int tid  = threadIdx.x;
    int lane = tid & 63;
    int wave = tid >> 6;

    int i0, i1;
    {
        int lo = 0, hi = n;
        while (lo < hi) { int mid = (lo + hi) >> 1; if (batch[mid] < g) lo = mid + 1; else hi = mid; }
        i0 = lo;
        lo = i0; hi = n;
        while (lo < hi) { int mid = (lo + hi) >> 1; if (batch[mid] < g + 1) lo = mid + 1; else hi = mid; }
        i1 = lo;
    }

    float s = 0.f;
    for (int i = i0 + wave; i < i1; i += 4) s += b2f(h[(size_t)i * GCN_F + lane]);

    __shared__ float sp[4][GCN_F];
    sp[wave][lane] = s;
    __syncthreads();
    if (wave == 0) {
        float tot = sp[0][lane] + sp[1][lane] + sp[2][lane] + sp[3][lane];
        float cntf = (float)(i1 - i0);
        sp[0][lane] = tot / fmaxf(cntf, 1.f);
    }
    __syncthreads();
    if (tid < GCN_C) {
        float o = bl[tid];
#pragma unroll
        for (int j = 0; j < GCN_F; ++j) o += sp[0][j] * Wl[j * GCN_C + tid];
        out[g * GCN_C + tid] = o;
    }
}

// --------------------------------------------------------------------------
extern "C" void kernel_launch(void* const* d_in, const int* in_sizes, int n_in,
                              void* d_out, int out_size, void* d_ws, size_t ws_size,
                              hipStream_t stream) {
    const float* x     = (const float*)d_in[0];
    const int*   ei    = (const int*)d_in[1];
    const float* ew    = (const float*)d_in[2];
    const int*   batch = (const int*)d_in[3];
    const float* W1r   = (const float*)d_in[4];
    const float* W1s   = (const float*)d_in[5];
    const float* b1    = (const float*)d_in[6];
    const float* W2r   = (const float*)d_in[7];
    const float* W2s   = (const float*)d_in[8];
    const float* b2    = (const float*)d_in[9];
    const float* W3r   = (const float*)d_in[10];
    const float* W3s   = (const float*)d_in[11];
    const float* b3    = (const float*)d_in[12];
    const float* Wl    = (const float*)d_in[13];
    const float* bl    = (const float*)d_in[14];
    float* out = (float*)d_out;

    const int N = in_sizes[0] / GCN_F;   // 100000
    const int E = in_sizes[2];           // 1000000
    const int G = out_size / GCN_C;      // 256

    const int* src = ei;
    const int* dst = ei + E;

    // workspace layout (16B aligned)
    char* ws = (char*)d_ws;
    size_t off = 0;
    int* cnt     = (int*)(ws + off);  off += (size_t)N * 4;
    int* cursor  = (int*)(ws + off);  off += (size_t)N * 4;             // adjacent: one memset
    int* offsets = (int*)(ws + off);  off += ((size_t)(N + 1) * 4 + 15) & ~(size_t)15;
    int* part    = (int*)(ws + off);  off += 4096;
    int2* sorted = (int2*)(ws + off); off += (size_t)E * 8;
    unsigned short* buf0 = (unsigned short*)(ws + off); off += (size_t)N * GCN_F * 2;  // x16 / h2
    unsigned short* agg  = (unsigned short*)(ws + off); off += (size_t)N * GCN_F * 2;
    unsigned short* hA   = (unsigned short*)(ws + off); off += (size_t)N * GCN_F * 2;  // h1 / h3

    int eblocks = (E + 255) / 256;
    int nscan   = (N + SCAN_CHUNK - 1) / SCAN_CHUNK;

    hipMemsetAsync(cnt, 0, (size_t)N * 8, stream);   // cnt + cursor
    hist_kernel<<<eblocks, 256, 0, stream>>>(dst, cnt, E);
    scan_part1<<<nscan, 256, 0, stream>>>(cnt, part, N);
    scan_part2<<<1, 64, 0, stream>>>(part, offsets, nscan, N);
    scan_final<<<nscan, 256, 0, stream>>>(cnt, part, offsets, N);
    scatter_kernel<<<eblocks, 256, 0, stream>>>(src, dst, ew, offsets, cursor, sorted, E);

    cvt_kernel<<<1024, 256, 0, stream>>>(x, buf0, N * GCN_F / 4);

    const int SBLK = 2048, GBLK = 800;
    // layer 1: in buf0 -> hA
    spmm_kernel<<<SBLK, 256, 0, stream>>>(buf0, offsets, sorted, agg, N);
    gemm_kernel<<<GBLK, 256, 0, stream>>>(agg, buf0, W1r, W1s, b1, hA, N);
    // layer 2: in hA -> buf0
    spmm_kernel<<<SBLK, 256, 0, stream>>>(hA, offsets, sorted, agg, N);
    gemm_kernel<<<GBLK, 256, 0, stream>>>(agg, hA, W2r, W2s, b2, buf0, N);
    // layer 3: in buf0 -> hA
    spmm_kernel<<<SBLK, 256, 0, stream>>>(buf0, offsets, sorted, agg, N);
    gemm_kernel<<<GBLK, 256, 0, stream>>>(agg, buf0, W3r, W3s, b3, hA, N);

    pool_kernel<<<G, 256, 0, stream>>>(hA, batch, Wl, bl, out, N);
}